// Round 11
// baseline (122.720 us; speedup 1.0000x reference)
//
#include <hip/hip_runtime.h>
#include <hip/hip_bf16.h>

// Problem constants
#define NUM_NODES 500000
#define DD  128
#define UU  32
#define TT  4
#define AA  32
#define NSRC 65536
#define BB  8192
#define EE  262144                  // = 2^18
#define NEDGE (TT * EE)             // 2^20
#define NBKT (BB * TT)              // 32768 buckets, id = dst*4 + t
#define CAP 64                      // slots per bucket (mean 32; overflow handled)
#define AGG_FLOATS (BB * TT * UU)
#define NB  16                      // output nodes per block in gather+node

__device__ __forceinline__ unsigned short f2bf(float f) {
    unsigned int u = __float_as_uint(f);
    unsigned int r = (u + 0x7FFFu + ((u >> 16) & 1u)) >> 16;   // RTNE
    return (unsigned short)r;
}

// ---- K1: zero counters (blocks 0..31) + build bf16 feats (rest) ---------
__global__ __launch_bounds__(256) void prep_kernel(
    const float4* __restrict__ nte4,         // [NUM_NODES][32] float4
    const int* __restrict__ input_nodes,     // [NSRC]
    unsigned short* __restrict__ feats,      // [T][NSRC][32] bf16
    int* __restrict__ cnt,                   // [NBKT]
    int* __restrict__ ovfCnt)
{
    int b = blockIdx.x;
    if (b < 32) {
        int i = b * 256 + threadIdx.x;       // 8192 int4 = NBKT ints
        ((int4*)cnt)[i] = make_int4(0, 0, 0, 0);
        if (b == 0 && threadIdx.x == 0) *ovfCnt = 0;
        return;
    }
    int gtid = (b - 32) * 256 + threadIdx.x; // T*NSRC*8 = 2M
    int src = gtid >> 5;
    int t = (gtid >> 3) & 3;
    int q = gtid & 7;
    long node = input_nodes[src];
    float4 v = nte4[node * 32 + t * 8 + q];
    ushort4 o;
    o.x = f2bf(v.x); o.y = f2bf(v.y); o.z = f2bf(v.z); o.w = f2bf(v.w);
    *(ushort4*)(feats + (((size_t)t * NSRC + src) << 5) + (q << 2)) = o;
}

// ---- K2: place each edge's src into its bucket's slot array -------------
__global__ __launch_bounds__(256) void place_kernel(
    const int* __restrict__ edge_src,
    const int* __restrict__ edge_dst,
    int* __restrict__ cnt,
    int* __restrict__ slots,                 // [NBKT][CAP]
    int* __restrict__ ovfCnt,
    int* __restrict__ ovf)                   // [NEDGE][2] worst case
{
    int i = blockIdx.x * 256 + threadIdx.x;  // edge id
    int k = edge_dst[i] * 4 + (i >> 18);
    int src = edge_src[i];
    int pos = atomicAdd(&cnt[k], 1);
    if (pos < CAP) {
        slots[k * CAP + pos] = src;
    } else {                                  // rare; fixed up in K3
        int o = atomicAdd(ovfCnt, 1);
        ovf[2 * o] = k; ovf[2 * o + 1] = src;
    }
}

// ---- K3: gather buckets into LDS + attention + transform + normalize ----
// 1024 threads = 16 waves; wave wv gathers dst b0+wv (its 4 t-buckets).
// w staged in LDS (not VGPRs) so 2 blocks/CU fit (32 waves/CU).
__global__ __launch_bounds__(1024, 8) void gather_node_kernel(
    const unsigned short* __restrict__ feats,  // [T][NSRC][32] bf16
    const int* __restrict__ slots,
    const int* __restrict__ cnt,
    const int* __restrict__ ovf,
    const int* __restrict__ ovfCnt,
    const float* __restrict__ node_emb,        // [NUM_NODES][D]
    const float* __restrict__ w,               // [T][U][D]
    const float* __restrict__ s1,              // [T][U][A]
    const float* __restrict__ s2,              // [T][A]
    const int* __restrict__ output_nodes,      // [B]
    float* __restrict__ out)                   // [B][T][D]
{
    __shared__ float s_w[TT][UU][DD];      // 64 KB
    __shared__ float s_nte[NB][TT * UU];   // 8 KB
    __shared__ float s_comb[NB][UU];       // 2 KB
    __shared__ float s_sc[NB][TT];
    __shared__ int   s_node[NB];
    __shared__ int   s_ovf;

    int tid  = threadIdx.x;
    int wv   = tid >> 6;                   // 0..15
    int lane = tid & 63;
    int b0   = blockIdx.x * NB;
    int e8 = lane >> 3, q = lane & 7;

    // stage w into LDS: 16384 floats = 4096 float4
    {
        const float4* w4 = (const float4*)w;
        float4* sw4 = (float4*)s_w;
        #pragma unroll
        for (int i = 0; i < 4; ++i)
            sw4[tid + i * 1024] = w4[tid + i * 1024];
    }

    // ---- gather: wave wv covers dst b0+wv, all 4 t (4 independent chains)
    {
        int dst = b0 + wv;
        #pragma unroll
        for (int t = 0; t < 4; ++t) {
            int k = dst * 4 + t;
            int n = cnt[k];
            int nslot = min(n, CAP);
            const uint2* rows = (const uint2*)(feats + ((size_t)t * NSRC << 5)) + q;
            float a0 = 0.f, a1 = 0.f, a2 = 0.f, a3 = 0.f;
            // lane handles edge j = it*8 + e8; slot load is an 8-lane
            // broadcast (q-lanes share the address) -> coalesced 32B/iter.
            int nIter = (nslot + 7) >> 3;
            for (int it = 0; it < nIter; ++it) {
                int j = (it << 3) + e8;
                if (j < nslot) {
                    int s = slots[k * CAP + j];
                    uint2 vv = rows[(size_t)s * 8];
                    a0 += __uint_as_float(vv.x << 16);
                    a1 += __uint_as_float(vv.x & 0xffff0000u);
                    a2 += __uint_as_float(vv.y << 16);
                    a3 += __uint_as_float(vv.y & 0xffff0000u);
                }
            }
            #pragma unroll
            for (int m = 8; m < 64; m <<= 1) {
                a0 += __shfl_xor(a0, m, 64);
                a1 += __shfl_xor(a1, m, 64);
                a2 += __shfl_xor(a2, m, 64);
                a3 += __shfl_xor(a3, m, 64);
            }
            if (lane < 8)
                ((float4*)&s_nte[wv][t * 32])[lane] = make_float4(a0, a1, a2, a3);
        }
    }
    if (tid < NB) s_node[tid] = output_nodes[b0 + tid];
    if (tid == 0) s_ovf = *ovfCnt;
    __syncthreads();

    // ---- overflow fix-up (rare; correctness only) ----
    if (s_ovf > 0) {
        for (int r = tid; r < s_ovf; r += 1024) {
            int k = ovf[2 * r];
            int dst = k >> 2;
            if (dst >= b0 && dst < b0 + NB) {
                int src = ovf[2 * r + 1];
                int t = k & 3, bl = dst - b0;
                const unsigned short* row = feats + (((size_t)t * NSRC + src) << 5);
                for (int u = 0; u < UU; ++u)
                    atomicAdd(&s_nte[bl][t * 32 + u],
                              __uint_as_float((unsigned)row[u] << 16));
            }
        }
        __syncthreads();
    }

    // ---- Phase A: attention scores; wave wv handles bl = wv ----
    int a  = lane & 31;
    int th = lane >> 5;
    int t0 = th, t1 = th + 2;
    {
        int bl = wv;
        float acc0 = 0.f, acc1 = 0.f;
        #pragma unroll
        for (int u = 0; u < UU; ++u) {
            acc0 += s_nte[bl][t0 * UU + u] * s1[(t0 * UU + u) * AA + a];
            acc1 += s_nte[bl][t1 * UU + u] * s1[(t1 * UU + u) * AA + a];
        }
        float p0 = tanhf(acc0) * s2[t0 * AA + a];
        float p1 = tanhf(acc1) * s2[t1 * AA + a];
        #pragma unroll
        for (int m = 1; m < 32; m <<= 1) {
            p0 += __shfl_xor(p0, m, 64);
            p1 += __shfl_xor(p1, m, 64);
        }
        if ((lane & 31) == 0) { s_sc[bl][th] = p0; s_sc[bl][th + 2] = p1; }
    }
    __syncthreads();

    // softmax + combined; wave wv handles bl = wv
    {
        int bl = wv;
        float sc0 = s_sc[bl][0], sc1 = s_sc[bl][1];
        float sc2 = s_sc[bl][2], sc3 = s_sc[bl][3];
        float mx = fmaxf(fmaxf(sc0, sc1), fmaxf(sc2, sc3));
        float e0 = expf(sc0 - mx), e1 = expf(sc1 - mx);
        float e2 = expf(sc2 - mx), e3 = expf(sc3 - mx);
        float isum = 1.f / (e0 + e1 + e2 + e3);
        if (lane < 32) {
            float c = e0 * isum * s_nte[bl][a]
                    + e1 * isum * s_nte[bl][UU + a]
                    + e2 * isum * s_nte[bl][2 * UU + a]
                    + e3 * isum * s_nte[bl][3 * UU + a];
            s_comb[bl][a] = c;
        }
    }
    __syncthreads();

    // ---- Phase B: wave = (t, group); each wave does 4 bl's; w from LDS ----
    int t   = wv & 3;
    int grp = wv >> 2;
    #pragma unroll
    for (int j = 0; j < 4; ++j) {
        int bl = grp * 4 + j;
        int node = s_node[bl];
        float accA = node_emb[(long)node * DD + lane];
        float accB = node_emb[(long)node * DD + lane + 64];
        #pragma unroll
        for (int u = 0; u < UU; ++u) {
            float c = s_comb[bl][u];
            accA += c * s_w[t][u][lane];
            accB += c * s_w[t][u][lane + 64];
        }
        float sq = accA * accA + accB * accB;
        #pragma unroll
        for (int m = 1; m < 64; m <<= 1)
            sq += __shfl_xor(sq, m, 64);
        float invn = 1.f / fmaxf(sqrtf(sq), 1e-12f);
        int ob = (b0 + bl) * (TT * DD) + t * DD;
        out[ob + lane]      = accA * invn;
        out[ob + lane + 64] = accB * invn;
    }
}

// ===================== fallback path (proven R2 structure) ===============
__global__ __launch_bounds__(256) void zero_agg_kernel(float4* __restrict__ p) {
    int i = blockIdx.x * 256 + threadIdx.x;
    p[i] = make_float4(0.f, 0.f, 0.f, 0.f);
}

__global__ __launch_bounds__(256) void edge_atomic_kernel(
    const float* __restrict__ nte_in,
    const int* __restrict__ input_nodes,
    const int* __restrict__ edge_src,
    const int* __restrict__ edge_dst,
    float* __restrict__ agg)
{
    int tid = blockIdx.x * 256 + threadIdx.x;
    int i = tid >> 5;
    int u = tid & 31;
    int t = i >> 18;
    int src = edge_src[i];
    int dst = edge_dst[i];
    int node = input_nodes[src];
    float v = nte_in[(long)node * 128 + t * 32 + u];
    atomicAdd(&agg[dst * 128 + t * 32 + u], v);
}

__global__ __launch_bounds__(256) void node_kernel(
    const float* __restrict__ node_emb,
    const float* __restrict__ w,
    const float* __restrict__ s1,
    const float* __restrict__ s2,
    const int* __restrict__ output_nodes,
    const float* __restrict__ agg,
    float* __restrict__ out)
{
    __shared__ float s_nte[NB][TT * UU];
    __shared__ float s_comb[NB][UU];
    __shared__ float s_sc[NB][TT];
    __shared__ int   s_node[NB];

    int tid  = threadIdx.x;
    int wv   = tid >> 6;
    int lane = tid & 63;
    int b0   = blockIdx.x * NB;

    {
        const float4* av = (const float4*)(agg + b0 * 128);
        float4* sv = (float4*)&s_nte[0][0];
        sv[tid]       = av[tid];
        sv[tid + 256] = av[tid + 256];
    }
    if (tid < NB) s_node[tid] = output_nodes[b0 + tid];
    __syncthreads();

    int a  = lane & 31;
    int th = lane >> 5;
    int t0 = th, t1 = th + 2;
    float s1a[UU], s1b[UU];
    #pragma unroll
    for (int u = 0; u < UU; ++u) {
        s1a[u] = s1[(t0 * UU + u) * AA + a];
        s1b[u] = s1[(t1 * UU + u) * AA + a];
    }
    float s2a = s2[t0 * AA + a];
    float s2b = s2[t1 * AA + a];

    #pragma unroll
    for (int q = 0; q < 4; ++q) {
        int bl = wv * 4 + q;
        float acc0 = 0.f, acc1 = 0.f;
        #pragma unroll
        for (int u = 0; u < UU; ++u) {
            acc0 += s_nte[bl][t0 * UU + u] * s1a[u];
            acc1 += s_nte[bl][t1 * UU + u] * s1b[u];
        }
        float p0 = tanhf(acc0) * s2a;
        float p1 = tanhf(acc1) * s2b;
        #pragma unroll
        for (int m = 1; m < 32; m <<= 1) {
            p0 += __shfl_xor(p0, m, 64);
            p1 += __shfl_xor(p1, m, 64);
        }
        if ((lane & 31) == 0) { s_sc[bl][th] = p0; s_sc[bl][th + 2] = p1; }
    }
    __syncthreads();

    #pragma unroll
    for (int q = 0; q < 4; ++q) {
        int bl = wv * 4 + q;
        float sc0 = s_sc[bl][0], sc1 = s_sc[bl][1];
        float sc2 = s_sc[bl][2], sc3 = s_sc[bl][3];
        float mx = fmaxf(fmaxf(sc0, sc1), fmaxf(sc2, sc3));
        float e0 = expf(sc0 - mx), e1 = expf(sc1 - mx);
        float e2 = expf(sc2 - mx), e3 = expf(sc3 - mx);
        float isum = 1.f / (e0 + e1 + e2 + e3);
        if (lane < 32) {
            float c = e0 * isum * s_nte[bl][a]
                    + e1 * isum * s_nte[bl][UU + a]
                    + e2 * isum * s_nte[bl][2 * UU + a]
                    + e3 * isum * s_nte[bl][3 * UU + a];
            s_comb[bl][a] = c;
        }
    }
    __syncthreads();

    int t = wv;
    const float* wt = w + t * (UU * DD);
    float wA[UU], wB[UU];
    #pragma unroll
    for (int u = 0; u < UU; ++u) {
        wA[u] = wt[u * DD + lane];
        wB[u] = wt[u * DD + lane + 64];
    }
    for (int bl = 0; bl < NB; ++bl) {
        int node = s_node[bl];
        float accA = node_emb[(long)node * DD + lane];
        float accB = node_emb[(long)node * DD + lane + 64];
        #pragma unroll
        for (int u = 0; u < UU; ++u) {
            float c = s_comb[bl][u];
            accA += c * wA[u];
            accB += c * wB[u];
        }
        float sq = accA * accA + accB * accB;
        #pragma unroll
        for (int m = 1; m < 64; m <<= 1)
            sq += __shfl_xor(sq, m, 64);
        float invn = 1.f / fmaxf(sqrtf(sq), 1e-12f);
        int ob = (b0 + bl) * (TT * DD) + t * DD;
        out[ob + lane]      = accA * invn;
        out[ob + lane + 64] = accB * invn;
    }
}

// =========================================================================
extern "C" void kernel_launch(void* const* d_in, const int* in_sizes, int n_in,
                              void* d_out, int out_size, void* d_ws, size_t ws_size,
                              hipStream_t stream) {
    const float* node_emb = (const float*)d_in[0];
    const float* nte_in   = (const float*)d_in[1];
    const float* w        = (const float*)d_in[2];
    const float* s1       = (const float*)d_in[3];
    const float* s2       = (const float*)d_in[4];
    const int* input_nodes  = (const int*)d_in[5];
    const int* output_nodes = (const int*)d_in[6];
    const int* edge_src     = (const int*)d_in[7];
    const int* edge_dst     = (const int*)d_in[8];
    float* out = (float*)d_out;

    // workspace layout (main path)
    char* ws = (char*)d_ws;
    unsigned short* feats = (unsigned short*)ws;                      // 16 MB
    size_t off = (size_t)TT * NSRC * 32 * 2;
    int* slots  = (int*)(ws + off);          off += (size_t)NBKT * CAP * 4;  // 8 MB
    int* cnt    = (int*)(ws + off);          off += (size_t)NBKT * 4;        // 128 KB
    int* ovfCnt = (int*)(ws + off);          off += 256;
    int* ovf    = (int*)(ws + off);          off += (size_t)NEDGE * 2 * 4;   // 8 MB
    size_t need = off;

    if (ws_size >= need) {
        prep_kernel<<<dim3(32 + TT * NSRC * 8 / 256), dim3(256), 0, stream>>>(
            (const float4*)nte_in, input_nodes, feats, cnt, ovfCnt);
        place_kernel<<<dim3(NEDGE / 256), dim3(256), 0, stream>>>(
            edge_src, edge_dst, cnt, slots, ovfCnt, ovf);
        gather_node_kernel<<<dim3(BB / NB), dim3(1024), 0, stream>>>(
            feats, slots, cnt, ovf, ovfCnt,
            node_emb, w, s1, s2, output_nodes, out);
    } else {
        // fallback: proven direct-atomic 3-kernel path
        float* agg = (float*)d_ws;   // 4 MB
        zero_agg_kernel<<<dim3(AGG_FLOATS / 4 / 256), dim3(256), 0, stream>>>((float4*)agg);
        edge_atomic_kernel<<<dim3((NEDGE * 32) / 256), dim3(256), 0, stream>>>(
            nte_in, input_nodes, edge_src, edge_dst, agg);
        node_kernel<<<dim3(BB / NB), dim3(256), 0, stream>>>(
            node_emb, w, s1, s2, output_nodes, agg, out);
    }
}

// Round 12
// 112.699 us; speedup vs baseline: 1.0889x; 1.0889x over previous
//
#include <hip/hip_runtime.h>
#include <hip/hip_bf16.h>

// Problem constants
#define NUM_NODES 500000
#define DD  128
#define UU  32
#define TT  4
#define AA  32
#define NSRC 65536
#define BB  8192
#define EE  262144                  // = 2^18
#define NEDGE (TT * EE)             // 2^20
#define NBKT (BB * TT)              // 32768 buckets, id = dst*4 + t
#define CAP 128                     // slots per bucket (mean 32; P(overflow)~0)
#define AGG_FLOATS (BB * TT * UU)
#define NB  16                      // output nodes per block in gather+node

__device__ __forceinline__ unsigned short f2bf(float f) {
    unsigned int u = __float_as_uint(f);
    unsigned int r = (u + 0x7FFFu + ((u >> 16) & 1u)) >> 16;   // RTNE
    return (unsigned short)r;
}

// ---- K1: zero counters (blocks 0..31) + build bf16 feats (rest) ---------
__global__ __launch_bounds__(256) void prep_kernel(
    const float4* __restrict__ nte4,         // [NUM_NODES][32] float4
    const int* __restrict__ input_nodes,     // [NSRC]
    unsigned short* __restrict__ feats,      // [T][NSRC][32] bf16
    int* __restrict__ cnt,                   // [NBKT]
    int* __restrict__ ovfCnt)
{
    int b = blockIdx.x;
    if (b < 32) {
        int i = b * 256 + threadIdx.x;       // 8192 int4 = NBKT ints
        ((int4*)cnt)[i] = make_int4(0, 0, 0, 0);
        if (b == 0 && threadIdx.x == 0) *ovfCnt = 0;
        return;
    }
    int gtid = (b - 32) * 256 + threadIdx.x; // T*NSRC*8 = 2M
    int src = gtid >> 5;
    int t = (gtid >> 3) & 3;
    int q = gtid & 7;
    long node = input_nodes[src];
    float4 v = nte4[node * 32 + t * 8 + q];
    ushort4 o;
    o.x = f2bf(v.x); o.y = f2bf(v.y); o.z = f2bf(v.z); o.w = f2bf(v.w);
    *(ushort4*)(feats + (((size_t)t * NSRC + src) << 5) + (q << 2)) = o;
}

// ---- K2: place each edge's src into its bucket's slot array -------------
__global__ __launch_bounds__(256) void place_kernel(
    const int* __restrict__ edge_src,
    const int* __restrict__ edge_dst,
    int* __restrict__ cnt,
    int* __restrict__ slots,                 // [NBKT][CAP]
    int* __restrict__ ovfCnt,
    int* __restrict__ ovf)                   // [NEDGE][2] worst case
{
    int i = blockIdx.x * 256 + threadIdx.x;  // edge id
    int k = edge_dst[i] * 4 + (i >> 18);
    int src = edge_src[i];
    int pos = atomicAdd(&cnt[k], 1);
    if (pos < CAP) {
        slots[k * CAP + pos] = src;
    } else {                                  // essentially never
        int o = atomicAdd(ovfCnt, 1);
        ovf[2 * o] = k; ovf[2 * o + 1] = src;
    }
}

// ---- K3: gather buckets into LDS + attention + transform + normalize ----
// 1024 threads = 16 waves; wave wv gathers dst b0+wv (its 4 t-buckets).
__global__ __launch_bounds__(1024) void gather_node_kernel(
    const unsigned short* __restrict__ feats,  // [T][NSRC][32] bf16
    const int* __restrict__ slots,
    const int* __restrict__ cnt,
    const int* __restrict__ ovf,
    const int* __restrict__ ovfCnt,
    const float* __restrict__ node_emb,        // [NUM_NODES][D]
    const float* __restrict__ w,               // [T][U][D]
    const float* __restrict__ s1,              // [T][U][A]
    const float* __restrict__ s2,              // [T][A]
    const int* __restrict__ output_nodes,      // [B]
    float* __restrict__ out)                   // [B][T][D]
{
    __shared__ float s_nte[NB][TT * UU];   // 8 KB
    __shared__ float s_comb[NB][UU];
    __shared__ float s_sc[NB][TT];
    __shared__ int   s_node[NB];
    __shared__ int   s_ovf;

    int tid  = threadIdx.x;
    int wv   = tid >> 6;                   // 0..15
    int lane = tid & 63;
    int b0   = blockIdx.x * NB;
    int e8 = lane >> 3, q = lane & 7;

    // ---- gather: wave wv covers dst b0+wv, all 4 t (4 independent chains)
    {
        int dst = b0 + wv;
        #pragma unroll
        for (int t = 0; t < 4; ++t) {
            int k = dst * 4 + t;
            int n = cnt[k];
            int nslot = min(n, CAP);
            int pre = min(nslot, 64);
            int idx = slots[k * CAP + lane];   // coalesced; use guarded by j<pre
            const uint2* rows = (const uint2*)(feats + ((size_t)t * NSRC << 5)) + q;
            float a0 = 0.f, a1 = 0.f, a2 = 0.f, a3 = 0.f;
            int nIter = (pre + 7) >> 3;        // wave-uniform: shfl sources stay active
            for (int it = 0; it < nIter; ++it) {
                int j = (it << 3) + e8;
                int s = __shfl(idx, j, 64);
                if (j < pre) {
                    uint2 vv = rows[(size_t)s * 8];
                    a0 += __uint_as_float(vv.x << 16);
                    a1 += __uint_as_float(vv.x & 0xffff0000u);
                    a2 += __uint_as_float(vv.y << 16);
                    a3 += __uint_as_float(vv.y & 0xffff0000u);
                }
            }
            for (int j = 64 + e8; j < nslot; j += 8) {   // rare (n>64), direct loads
                int s = slots[k * CAP + j];
                uint2 vv = rows[(size_t)s * 8];
                a0 += __uint_as_float(vv.x << 16);
                a1 += __uint_as_float(vv.x & 0xffff0000u);
                a2 += __uint_as_float(vv.y << 16);
                a3 += __uint_as_float(vv.y & 0xffff0000u);
            }
            #pragma unroll
            for (int m = 8; m < 64; m <<= 1) {
                a0 += __shfl_xor(a0, m, 64);
                a1 += __shfl_xor(a1, m, 64);
                a2 += __shfl_xor(a2, m, 64);
                a3 += __shfl_xor(a3, m, 64);
            }
            if (lane < 8)
                ((float4*)&s_nte[wv][t * 32])[lane] = make_float4(a0, a1, a2, a3);
        }
    }
    if (tid < NB) s_node[tid] = output_nodes[b0 + tid];
    if (tid == 0) s_ovf = *ovfCnt;
    __syncthreads();

    // ---- overflow fix-up (never executes in practice; correctness only) ----
    if (s_ovf > 0) {
        for (int r = tid; r < s_ovf; r += 1024) {
            int k = ovf[2 * r];
            int dst = k >> 2;
            if (dst >= b0 && dst < b0 + NB) {
                int src = ovf[2 * r + 1];
                int t = k & 3, bl = dst - b0;
                const unsigned short* row = feats + (((size_t)t * NSRC + src) << 5);
                for (int u = 0; u < UU; ++u)
                    atomicAdd(&s_nte[bl][t * 32 + u],
                              __uint_as_float((unsigned)row[u] << 16));
            }
        }
        __syncthreads();
    }

    // ---- Phase A: attention scores; wave wv handles bl = wv ----
    int a  = lane & 31;
    int th = lane >> 5;
    int t0 = th, t1 = th + 2;
    {
        int bl = wv;
        float acc0 = 0.f, acc1 = 0.f;
        #pragma unroll
        for (int u = 0; u < UU; ++u) {
            acc0 += s_nte[bl][t0 * UU + u] * s1[(t0 * UU + u) * AA + a];
            acc1 += s_nte[bl][t1 * UU + u] * s1[(t1 * UU + u) * AA + a];
        }
        float p0 = tanhf(acc0) * s2[t0 * AA + a];
        float p1 = tanhf(acc1) * s2[t1 * AA + a];
        #pragma unroll
        for (int m = 1; m < 32; m <<= 1) {
            p0 += __shfl_xor(p0, m, 64);
            p1 += __shfl_xor(p1, m, 64);
        }
        if ((lane & 31) == 0) { s_sc[bl][th] = p0; s_sc[bl][th + 2] = p1; }
    }
    __syncthreads();

    // softmax + combined; wave wv handles bl = wv
    {
        int bl = wv;
        float sc0 = s_sc[bl][0], sc1 = s_sc[bl][1];
        float sc2 = s_sc[bl][2], sc3 = s_sc[bl][3];
        float mx = fmaxf(fmaxf(sc0, sc1), fmaxf(sc2, sc3));
        float e0 = expf(sc0 - mx), e1 = expf(sc1 - mx);
        float e2 = expf(sc2 - mx), e3 = expf(sc3 - mx);
        float isum = 1.f / (e0 + e1 + e2 + e3);
        if (lane < 32) {
            float c = e0 * isum * s_nte[bl][a]
                    + e1 * isum * s_nte[bl][UU + a]
                    + e2 * isum * s_nte[bl][2 * UU + a]
                    + e3 * isum * s_nte[bl][3 * UU + a];
            s_comb[bl][a] = c;
        }
    }
    __syncthreads();

    // ---- Phase B: wave = (t, group); each wave does 4 bl's ----
    int t   = wv & 3;
    int grp = wv >> 2;
    const float* wt = w + t * (UU * DD);
    float wA[UU], wB[UU];
    #pragma unroll
    for (int u = 0; u < UU; ++u) {
        wA[u] = wt[u * DD + lane];
        wB[u] = wt[u * DD + lane + 64];
    }
    #pragma unroll
    for (int j = 0; j < 4; ++j) {
        int bl = grp * 4 + j;
        int node = s_node[bl];
        float accA = node_emb[(long)node * DD + lane];
        float accB = node_emb[(long)node * DD + lane + 64];
        #pragma unroll
        for (int u = 0; u < UU; ++u) {
            float c = s_comb[bl][u];
            accA += c * wA[u];
            accB += c * wB[u];
        }
        float sq = accA * accA + accB * accB;
        #pragma unroll
        for (int m = 1; m < 64; m <<= 1)
            sq += __shfl_xor(sq, m, 64);
        float invn = 1.f / fmaxf(sqrtf(sq), 1e-12f);
        int ob = (b0 + bl) * (TT * DD) + t * DD;
        out[ob + lane]      = accA * invn;
        out[ob + lane + 64] = accB * invn;
    }
}

// ===================== fallback path (proven R2 structure) ===============
__global__ __launch_bounds__(256) void zero_agg_kernel(float4* __restrict__ p) {
    int i = blockIdx.x * 256 + threadIdx.x;
    p[i] = make_float4(0.f, 0.f, 0.f, 0.f);
}

__global__ __launch_bounds__(256) void edge_atomic_kernel(
    const float* __restrict__ nte_in,
    const int* __restrict__ input_nodes,
    const int* __restrict__ edge_src,
    const int* __restrict__ edge_dst,
    float* __restrict__ agg)
{
    int tid = blockIdx.x * 256 + threadIdx.x;
    int i = tid >> 5;
    int u = tid & 31;
    int t = i >> 18;
    int src = edge_src[i];
    int dst = edge_dst[i];
    int node = input_nodes[src];
    float v = nte_in[(long)node * 128 + t * 32 + u];
    atomicAdd(&agg[dst * 128 + t * 32 + u], v);
}

__global__ __launch_bounds__(256) void node_kernel(
    const float* __restrict__ node_emb,
    const float* __restrict__ w,
    const float* __restrict__ s1,
    const float* __restrict__ s2,
    const int* __restrict__ output_nodes,
    const float* __restrict__ agg,
    float* __restrict__ out)
{
    __shared__ float s_nte[NB][TT * UU];
    __shared__ float s_comb[NB][UU];
    __shared__ float s_sc[NB][TT];
    __shared__ int   s_node[NB];

    int tid  = threadIdx.x;
    int wv   = tid >> 6;
    int lane = tid & 63;
    int b0   = blockIdx.x * NB;

    {
        const float4* av = (const float4*)(agg + b0 * 128);
        float4* sv = (float4*)&s_nte[0][0];
        sv[tid]       = av[tid];
        sv[tid + 256] = av[tid + 256];
    }
    if (tid < NB) s_node[tid] = output_nodes[b0 + tid];
    __syncthreads();

    int a  = lane & 31;
    int th = lane >> 5;
    int t0 = th, t1 = th + 2;
    float s1a[UU], s1b[UU];
    #pragma unroll
    for (int u = 0; u < UU; ++u) {
        s1a[u] = s1[(t0 * UU + u) * AA + a];
        s1b[u] = s1[(t1 * UU + u) * AA + a];
    }
    float s2a = s2[t0 * AA + a];
    float s2b = s2[t1 * AA + a];

    #pragma unroll
    for (int q = 0; q < 4; ++q) {
        int bl = wv * 4 + q;
        float acc0 = 0.f, acc1 = 0.f;
        #pragma unroll
        for (int u = 0; u < UU; ++u) {
            acc0 += s_nte[bl][t0 * UU + u] * s1a[u];
            acc1 += s_nte[bl][t1 * UU + u] * s1b[u];
        }
        float p0 = tanhf(acc0) * s2a;
        float p1 = tanhf(acc1) * s2b;
        #pragma unroll
        for (int m = 1; m < 32; m <<= 1) {
            p0 += __shfl_xor(p0, m, 64);
            p1 += __shfl_xor(p1, m, 64);
        }
        if ((lane & 31) == 0) { s_sc[bl][th] = p0; s_sc[bl][th + 2] = p1; }
    }
    __syncthreads();

    #pragma unroll
    for (int q = 0; q < 4; ++q) {
        int bl = wv * 4 + q;
        float sc0 = s_sc[bl][0], sc1 = s_sc[bl][1];
        float sc2 = s_sc[bl][2], sc3 = s_sc[bl][3];
        float mx = fmaxf(fmaxf(sc0, sc1), fmaxf(sc2, sc3));
        float e0 = expf(sc0 - mx), e1 = expf(sc1 - mx);
        float e2 = expf(sc2 - mx), e3 = expf(sc3 - mx);
        float isum = 1.f / (e0 + e1 + e2 + e3);
        if (lane < 32) {
            float c = e0 * isum * s_nte[bl][a]
                    + e1 * isum * s_nte[bl][UU + a]
                    + e2 * isum * s_nte[bl][2 * UU + a]
                    + e3 * isum * s_nte[bl][3 * UU + a];
            s_comb[bl][a] = c;
        }
    }
    __syncthreads();

    int t = wv;
    const float* wt = w + t * (UU * DD);
    float wA[UU], wB[UU];
    #pragma unroll
    for (int u = 0; u < UU; ++u) {
        wA[u] = wt[u * DD + lane];
        wB[u] = wt[u * DD + lane + 64];
    }
    for (int bl = 0; bl < NB; ++bl) {
        int node = s_node[bl];
        float accA = node_emb[(long)node * DD + lane];
        float accB = node_emb[(long)node * DD + lane + 64];
        #pragma unroll
        for (int u = 0; u < UU; ++u) {
            float c = s_comb[bl][u];
            accA += c * wA[u];
            accB += c * wB[u];
        }
        float sq = accA * accA + accB * accB;
        #pragma unroll
        for (int m = 1; m < 64; m <<= 1)
            sq += __shfl_xor(sq, m, 64);
        float invn = 1.f / fmaxf(sqrtf(sq), 1e-12f);
        int ob = (b0 + bl) * (TT * DD) + t * DD;
        out[ob + lane]      = accA * invn;
        out[ob + lane + 64] = accB * invn;
    }
}

// =========================================================================
extern "C" void kernel_launch(void* const* d_in, const int* in_sizes, int n_in,
                              void* d_out, int out_size, void* d_ws, size_t ws_size,
                              hipStream_t stream) {
    const float* node_emb = (const float*)d_in[0];
    const float* nte_in   = (const float*)d_in[1];
    const float* w        = (const float*)d_in[2];
    const float* s1       = (const float*)d_in[3];
    const float* s2       = (const float*)d_in[4];
    const int* input_nodes  = (const int*)d_in[5];
    const int* output_nodes = (const int*)d_in[6];
    const int* edge_src     = (const int*)d_in[7];
    const int* edge_dst     = (const int*)d_in[8];
    float* out = (float*)d_out;

    // workspace layout (main path)
    char* ws = (char*)d_ws;
    unsigned short* feats = (unsigned short*)ws;                      // 16 MB
    size_t off = (size_t)TT * NSRC * 32 * 2;
    int* slots  = (int*)(ws + off);          off += (size_t)NBKT * CAP * 4;  // 16 MB
    int* cnt    = (int*)(ws + off);          off += (size_t)NBKT * 4;        // 128 KB
    int* ovfCnt = (int*)(ws + off);          off += 256;
    int* ovf    = (int*)(ws + off);          off += (size_t)NEDGE * 2 * 4;   // 8 MB
    size_t need = off;

    if (ws_size >= need) {
        prep_kernel<<<dim3(32 + TT * NSRC * 8 / 256), dim3(256), 0, stream>>>(
            (const float4*)nte_in, input_nodes, feats, cnt, ovfCnt);
        place_kernel<<<dim3(NEDGE / 256), dim3(256), 0, stream>>>(
            edge_src, edge_dst, cnt, slots, ovfCnt, ovf);
        gather_node_kernel<<<dim3(BB / NB), dim3(1024), 0, stream>>>(
            feats, slots, cnt, ovf, ovfCnt,
            node_emb, w, s1, s2, output_nodes, out);
    } else {
        // fallback: proven direct-atomic 3-kernel path
        float* agg = (float*)d_ws;   // 4 MB
        zero_agg_kernel<<<dim3(AGG_FLOATS / 4 / 256), dim3(256), 0, stream>>>((float4*)agg);
        edge_atomic_kernel<<<dim3((NEDGE * 32) / 256), dim3(256), 0, stream>>>(
            nte_in, input_nodes, edge_src, edge_dst, agg);
        node_kernel<<<dim3(BB / NB), dim3(256), 0, stream>>>(
            node_emb, w, s1, s2, output_nodes, agg, out);
    }
}

// Round 13
// 107.882 us; speedup vs baseline: 1.1375x; 1.0446x over previous
//
#include <hip/hip_runtime.h>
#include <hip/hip_bf16.h>

// Problem constants
#define NUM_NODES 500000
#define DD  128
#define UU  32
#define TT  4
#define AA  32
#define NSRC 65536
#define BB  8192
#define EE  262144                  // = 2^18
#define NEDGE (TT * EE)             // 2^20
#define NBKT (BB * TT)              // 32768 buckets, id = dst*4 + t
#define CAP 128                     // slots per bucket (mean 32; P(overflow)~0)
#define AGG_FLOATS (BB * TT * UU)
#define NB  16                      // output nodes per block in gather+node

__device__ __forceinline__ unsigned short f2bf(float f) {
    unsigned int u = __float_as_uint(f);
    unsigned int r = (u + 0x7FFFu + ((u >> 16) & 1u)) >> 16;   // RTNE
    return (unsigned short)r;
}

// ---- K1: merged feats-build + edge-place (independent workloads) --------
// 12288 blocks: blockIdx%3<2 -> feats (8192 block-equivs),
//               blockIdx%3==2 -> place (4096 block-equivs).
// Interleaved so both latency-bound phases are co-resident and overlap.
// Requires cnt/ovfCnt pre-zeroed (hipMemsetAsync before this kernel).
__global__ __launch_bounds__(256) void feats_place_kernel(
    const float4* __restrict__ nte4,         // [NUM_NODES][32] float4
    const int* __restrict__ input_nodes,     // [NSRC]
    const int* __restrict__ edge_src,        // [NEDGE]
    const int* __restrict__ edge_dst,        // [NEDGE]
    unsigned short* __restrict__ feats,      // [T][NSRC][32] bf16
    int* __restrict__ cnt,                   // [NBKT] (pre-zeroed)
    int* __restrict__ slots,                 // [NBKT][CAP]
    int* __restrict__ ovfCnt,                // (pre-zeroed)
    int* __restrict__ ovf)                   // [NEDGE][2] worst case
{
    int b = blockIdx.x;
    int r = b % 3;
    if (r < 2) {
        // ---- feats: gtid in [0, T*NSRC*8) ----
        int fb = (b / 3) * 2 + r;            // 0..8191
        int gtid = fb * 256 + threadIdx.x;
        int src = gtid >> 5;
        int t = (gtid >> 3) & 3;
        int q = gtid & 7;
        long node = input_nodes[src];
        float4 v = nte4[node * 32 + t * 8 + q];
        ushort4 o;
        o.x = f2bf(v.x); o.y = f2bf(v.y); o.z = f2bf(v.z); o.w = f2bf(v.w);
        *(ushort4*)(feats + (((size_t)t * NSRC + src) << 5) + (q << 2)) = o;
    } else {
        // ---- place: edge i in [0, NEDGE) ----
        int pb = b / 3;                      // 0..4095
        int i = pb * 256 + threadIdx.x;
        int k = edge_dst[i] * 4 + (i >> 18);
        int src = edge_src[i];
        int pos = atomicAdd(&cnt[k], 1);
        if (pos < CAP) {
            slots[k * CAP + pos] = src;
        } else {                              // essentially never
            int o = atomicAdd(ovfCnt, 1);
            ovf[2 * o] = k; ovf[2 * o + 1] = src;
        }
    }
}

// ---- K2: gather buckets into LDS + attention + transform + normalize ----
// 1024 threads = 16 waves; wave wv gathers dst b0+wv (its 4 t-buckets).
// (unchanged from R12's proven 112.7 µs kernel)
__global__ __launch_bounds__(1024) void gather_node_kernel(
    const unsigned short* __restrict__ feats,  // [T][NSRC][32] bf16
    const int* __restrict__ slots,
    const int* __restrict__ cnt,
    const int* __restrict__ ovf,
    const int* __restrict__ ovfCnt,
    const float* __restrict__ node_emb,        // [NUM_NODES][D]
    const float* __restrict__ w,               // [T][U][D]
    const float* __restrict__ s1,              // [T][U][A]
    const float* __restrict__ s2,              // [T][A]
    const int* __restrict__ output_nodes,      // [B]
    float* __restrict__ out)                   // [B][T][D]
{
    __shared__ float s_nte[NB][TT * UU];   // 8 KB
    __shared__ float s_comb[NB][UU];
    __shared__ float s_sc[NB][TT];
    __shared__ int   s_node[NB];
    __shared__ int   s_ovf;

    int tid  = threadIdx.x;
    int wv   = tid >> 6;                   // 0..15
    int lane = tid & 63;
    int b0   = blockIdx.x * NB;
    int e8 = lane >> 3, q = lane & 7;

    // ---- gather: wave wv covers dst b0+wv, all 4 t (4 independent chains)
    {
        int dst = b0 + wv;
        #pragma unroll
        for (int t = 0; t < 4; ++t) {
            int k = dst * 4 + t;
            int n = cnt[k];
            int nslot = min(n, CAP);
            int pre = min(nslot, 64);
            int idx = slots[k * CAP + lane];   // coalesced; use guarded by j<pre
            const uint2* rows = (const uint2*)(feats + ((size_t)t * NSRC << 5)) + q;
            float a0 = 0.f, a1 = 0.f, a2 = 0.f, a3 = 0.f;
            int nIter = (pre + 7) >> 3;        // wave-uniform: shfl sources stay active
            for (int it = 0; it < nIter; ++it) {
                int j = (it << 3) + e8;
                int s = __shfl(idx, j, 64);
                if (j < pre) {
                    uint2 vv = rows[(size_t)s * 8];
                    a0 += __uint_as_float(vv.x << 16);
                    a1 += __uint_as_float(vv.x & 0xffff0000u);
                    a2 += __uint_as_float(vv.y << 16);
                    a3 += __uint_as_float(vv.y & 0xffff0000u);
                }
            }
            for (int j = 64 + e8; j < nslot; j += 8) {   // rare (n>64), direct loads
                int s = slots[k * CAP + j];
                uint2 vv = rows[(size_t)s * 8];
                a0 += __uint_as_float(vv.x << 16);
                a1 += __uint_as_float(vv.x & 0xffff0000u);
                a2 += __uint_as_float(vv.y << 16);
                a3 += __uint_as_float(vv.y & 0xffff0000u);
            }
            #pragma unroll
            for (int m = 8; m < 64; m <<= 1) {
                a0 += __shfl_xor(a0, m, 64);
                a1 += __shfl_xor(a1, m, 64);
                a2 += __shfl_xor(a2, m, 64);
                a3 += __shfl_xor(a3, m, 64);
            }
            if (lane < 8)
                ((float4*)&s_nte[wv][t * 32])[lane] = make_float4(a0, a1, a2, a3);
        }
    }
    if (tid < NB) s_node[tid] = output_nodes[b0 + tid];
    if (tid == 0) s_ovf = *ovfCnt;
    __syncthreads();

    // ---- overflow fix-up (never executes in practice; correctness only) ----
    if (s_ovf > 0) {
        for (int r = tid; r < s_ovf; r += 1024) {
            int k = ovf[2 * r];
            int dst = k >> 2;
            if (dst >= b0 && dst < b0 + NB) {
                int src = ovf[2 * r + 1];
                int t = k & 3, bl = dst - b0;
                const unsigned short* row = feats + (((size_t)t * NSRC + src) << 5);
                for (int u = 0; u < UU; ++u)
                    atomicAdd(&s_nte[bl][t * 32 + u],
                              __uint_as_float((unsigned)row[u] << 16));
            }
        }
        __syncthreads();
    }

    // ---- Phase A: attention scores; wave wv handles bl = wv ----
    int a  = lane & 31;
    int th = lane >> 5;
    int t0 = th, t1 = th + 2;
    {
        int bl = wv;
        float acc0 = 0.f, acc1 = 0.f;
        #pragma unroll
        for (int u = 0; u < UU; ++u) {
            acc0 += s_nte[bl][t0 * UU + u] * s1[(t0 * UU + u) * AA + a];
            acc1 += s_nte[bl][t1 * UU + u] * s1[(t1 * UU + u) * AA + a];
        }
        float p0 = tanhf(acc0) * s2[t0 * AA + a];
        float p1 = tanhf(acc1) * s2[t1 * AA + a];
        #pragma unroll
        for (int m = 1; m < 32; m <<= 1) {
            p0 += __shfl_xor(p0, m, 64);
            p1 += __shfl_xor(p1, m, 64);
        }
        if ((lane & 31) == 0) { s_sc[bl][th] = p0; s_sc[bl][th + 2] = p1; }
    }
    __syncthreads();

    // softmax + combined; wave wv handles bl = wv
    {
        int bl = wv;
        float sc0 = s_sc[bl][0], sc1 = s_sc[bl][1];
        float sc2 = s_sc[bl][2], sc3 = s_sc[bl][3];
        float mx = fmaxf(fmaxf(sc0, sc1), fmaxf(sc2, sc3));
        float e0 = expf(sc0 - mx), e1 = expf(sc1 - mx);
        float e2 = expf(sc2 - mx), e3 = expf(sc3 - mx);
        float isum = 1.f / (e0 + e1 + e2 + e3);
        if (lane < 32) {
            float c = e0 * isum * s_nte[bl][a]
                    + e1 * isum * s_nte[bl][UU + a]
                    + e2 * isum * s_nte[bl][2 * UU + a]
                    + e3 * isum * s_nte[bl][3 * UU + a];
            s_comb[bl][a] = c;
        }
    }
    __syncthreads();

    // ---- Phase B: wave = (t, group); each wave does 4 bl's ----
    int t   = wv & 3;
    int grp = wv >> 2;
    const float* wt = w + t * (UU * DD);
    float wA[UU], wB[UU];
    #pragma unroll
    for (int u = 0; u < UU; ++u) {
        wA[u] = wt[u * DD + lane];
        wB[u] = wt[u * DD + lane + 64];
    }
    #pragma unroll
    for (int j = 0; j < 4; ++j) {
        int bl = grp * 4 + j;
        int node = s_node[bl];
        float accA = node_emb[(long)node * DD + lane];
        float accB = node_emb[(long)node * DD + lane + 64];
        #pragma unroll
        for (int u = 0; u < UU; ++u) {
            float c = s_comb[bl][u];
            accA += c * wA[u];
            accB += c * wB[u];
        }
        float sq = accA * accA + accB * accB;
        #pragma unroll
        for (int m = 1; m < 64; m <<= 1)
            sq += __shfl_xor(sq, m, 64);
        float invn = 1.f / fmaxf(sqrtf(sq), 1e-12f);
        int ob = (b0 + bl) * (TT * DD) + t * DD;
        out[ob + lane]      = accA * invn;
        out[ob + lane + 64] = accB * invn;
    }
}

// ===================== fallback path (proven R2 structure) ===============
__global__ __launch_bounds__(256) void zero_agg_kernel(float4* __restrict__ p) {
    int i = blockIdx.x * 256 + threadIdx.x;
    p[i] = make_float4(0.f, 0.f, 0.f, 0.f);
}

__global__ __launch_bounds__(256) void edge_atomic_kernel(
    const float* __restrict__ nte_in,
    const int* __restrict__ input_nodes,
    const int* __restrict__ edge_src,
    const int* __restrict__ edge_dst,
    float* __restrict__ agg)
{
    int tid = blockIdx.x * 256 + threadIdx.x;
    int i = tid >> 5;
    int u = tid & 31;
    int t = i >> 18;
    int src = edge_src[i];
    int dst = edge_dst[i];
    int node = input_nodes[src];
    float v = nte_in[(long)node * 128 + t * 32 + u];
    atomicAdd(&agg[dst * 128 + t * 32 + u], v);
}

__global__ __launch_bounds__(256) void node_kernel(
    const float* __restrict__ node_emb,
    const float* __restrict__ w,
    const float* __restrict__ s1,
    const float* __restrict__ s2,
    const int* __restrict__ output_nodes,
    const float* __restrict__ agg,
    float* __restrict__ out)
{
    __shared__ float s_nte[NB][TT * UU];
    __shared__ float s_comb[NB][UU];
    __shared__ float s_sc[NB][TT];
    __shared__ int   s_node[NB];

    int tid  = threadIdx.x;
    int wv   = tid >> 6;
    int lane = tid & 63;
    int b0   = blockIdx.x * NB;

    {
        const float4* av = (const float4*)(agg + b0 * 128);
        float4* sv = (float4*)&s_nte[0][0];
        sv[tid]       = av[tid];
        sv[tid + 256] = av[tid + 256];
    }
    if (tid < NB) s_node[tid] = output_nodes[b0 + tid];
    __syncthreads();

    int a  = lane & 31;
    int th = lane >> 5;
    int t0 = th, t1 = th + 2;
    float s1a[UU], s1b[UU];
    #pragma unroll
    for (int u = 0; u < UU; ++u) {
        s1a[u] = s1[(t0 * UU + u) * AA + a];
        s1b[u] = s1[(t1 * UU + u) * AA + a];
    }
    float s2a = s2[t0 * AA + a];
    float s2b = s2[t1 * AA + a];

    #pragma unroll
    for (int q = 0; q < 4; ++q) {
        int bl = wv * 4 + q;
        float acc0 = 0.f, acc1 = 0.f;
        #pragma unroll
        for (int u = 0; u < UU; ++u) {
            acc0 += s_nte[bl][t0 * UU + u] * s1a[u];
            acc1 += s_nte[bl][t1 * UU + u] * s1b[u];
        }
        float p0 = tanhf(acc0) * s2a;
        float p1 = tanhf(acc1) * s2b;
        #pragma unroll
        for (int m = 1; m < 32; m <<= 1) {
            p0 += __shfl_xor(p0, m, 64);
            p1 += __shfl_xor(p1, m, 64);
        }
        if ((lane & 31) == 0) { s_sc[bl][th] = p0; s_sc[bl][th + 2] = p1; }
    }
    __syncthreads();

    #pragma unroll
    for (int q = 0; q < 4; ++q) {
        int bl = wv * 4 + q;
        float sc0 = s_sc[bl][0], sc1 = s_sc[bl][1];
        float sc2 = s_sc[bl][2], sc3 = s_sc[bl][3];
        float mx = fmaxf(fmaxf(sc0, sc1), fmaxf(sc2, sc3));
        float e0 = expf(sc0 - mx), e1 = expf(sc1 - mx);
        float e2 = expf(sc2 - mx), e3 = expf(sc3 - mx);
        float isum = 1.f / (e0 + e1 + e2 + e3);
        if (lane < 32) {
            float c = e0 * isum * s_nte[bl][a]
                    + e1 * isum * s_nte[bl][UU + a]
                    + e2 * isum * s_nte[bl][2 * UU + a]
                    + e3 * isum * s_nte[bl][3 * UU + a];
            s_comb[bl][a] = c;
        }
    }
    __syncthreads();

    int t = wv;
    const float* wt = w + t * (UU * DD);
    float wA[UU], wB[UU];
    #pragma unroll
    for (int u = 0; u < UU; ++u) {
        wA[u] = wt[u * DD + lane];
        wB[u] = wt[u * DD + lane + 64];
    }
    for (int bl = 0; bl < NB; ++bl) {
        int node = s_node[bl];
        float accA = node_emb[(long)node * DD + lane];
        float accB = node_emb[(long)node * DD + lane + 64];
        #pragma unroll
        for (int u = 0; u < UU; ++u) {
            float c = s_comb[bl][u];
            accA += c * wA[u];
            accB += c * wB[u];
        }
        float sq = accA * accA + accB * accB;
        #pragma unroll
        for (int m = 1; m < 64; m <<= 1)
            sq += __shfl_xor(sq, m, 64);
        float invn = 1.f / fmaxf(sqrtf(sq), 1e-12f);
        int ob = (b0 + bl) * (TT * DD) + t * DD;
        out[ob + lane]      = accA * invn;
        out[ob + lane + 64] = accB * invn;
    }
}

// =========================================================================
extern "C" void kernel_launch(void* const* d_in, const int* in_sizes, int n_in,
                              void* d_out, int out_size, void* d_ws, size_t ws_size,
                              hipStream_t stream) {
    const float* node_emb = (const float*)d_in[0];
    const float* nte_in   = (const float*)d_in[1];
    const float* w        = (const float*)d_in[2];
    const float* s1       = (const float*)d_in[3];
    const float* s2       = (const float*)d_in[4];
    const int* input_nodes  = (const int*)d_in[5];
    const int* output_nodes = (const int*)d_in[6];
    const int* edge_src     = (const int*)d_in[7];
    const int* edge_dst     = (const int*)d_in[8];
    float* out = (float*)d_out;

    // workspace layout (main path): feats | slots | cnt | ovfCnt | ovf
    char* ws = (char*)d_ws;
    unsigned short* feats = (unsigned short*)ws;                      // 16 MB
    size_t off = (size_t)TT * NSRC * 32 * 2;
    int* slots  = (int*)(ws + off);          off += (size_t)NBKT * CAP * 4;  // 16 MB
    int* cnt    = (int*)(ws + off);          off += (size_t)NBKT * 4;        // 128 KB
    int* ovfCnt = (int*)(ws + off);          off += 256;                     // (zeroed with cnt)
    int* ovf    = (int*)(ws + off);          off += (size_t)NEDGE * 2 * 4;   // 8 MB
    size_t need = off;

    if (ws_size >= need) {
        // zero cnt + ovfCnt in one stream-ordered fill (graph-capturable)
        hipMemsetAsync(cnt, 0, (size_t)NBKT * 4 + 256, stream);
        feats_place_kernel<<<dim3(12288), dim3(256), 0, stream>>>(
            (const float4*)nte_in, input_nodes, edge_src, edge_dst,
            feats, cnt, slots, ovfCnt, ovf);
        gather_node_kernel<<<dim3(BB / NB), dim3(1024), 0, stream>>>(
            feats, slots, cnt, ovf, ovfCnt,
            node_emb, w, s1, s2, output_nodes, out);
    } else {
        // fallback: proven direct-atomic 3-kernel path
        float* agg = (float*)d_ws;   // 4 MB
        zero_agg_kernel<<<dim3(AGG_FLOATS / 4 / 256), dim3(256), 0, stream>>>((float4*)agg);
        edge_atomic_kernel<<<dim3((NEDGE * 32) / 256), dim3(256), 0, stream>>>(
            nte_in, input_nodes, edge_src, edge_dst, agg);
        node_kernel<<<dim3(BB / NB), dim3(256), 0, stream>>>(
            node_emb, w, s1, s2, output_nodes, agg, out);
    }
}